// Round 6
// baseline (194.909 us; speedup 1.0000x reference)
//
#include <hip/hip_runtime.h>
#include <hip/hip_bf16.h>
#include <math.h>

#define BN 4
#define CIN 128
#define HH 32
#define WW 32
#define HWP 1024
#define NHEAD 8

typedef __attribute__((ext_vector_type(8))) short s8v;
typedef __attribute__((ext_vector_type(4))) float f32x4;

__device__ __forceinline__ float bf2f(short h) {
    union { unsigned u; float f; } v;
    v.u = ((unsigned)(unsigned short)h) << 16;
    return v.f;
}

// ---------------- P1: x (NCHW fp32) -> xT[b][34][34][128] bf16, zero halo ----
__global__ __launch_bounds__(256) void prep_xT(
    const float* __restrict__ x, __hip_bfloat16* __restrict__ xT)
{
    __shared__ float xs[CIN][33];
    const int yy = blockIdx.x;
    const int b = blockIdx.y;
    const int tid = threadIdx.x;
    const bool inner = (yy >= 1 && yy <= 32);

    if (inner) {
        for (int idx = tid; idx < CIN * 32; idx += 256) {
            int ci = idx >> 5, xx = idx & 31;
            xs[ci][xx] = x[((size_t)(b * CIN + ci) * HH + (yy - 1)) * WW + xx];
        }
    }
    __syncthreads();

    for (int idx = tid; idx < 34 * 128; idx += 256) {
        int xx = idx >> 7, ci = idx & 127;
        float v = 0.f;
        if (inner && xx >= 1 && xx <= 32) v = xs[ci][xx - 1];
        xT[((size_t)(b * 34 + yy) * 34 + xx) * 128 + ci] = __float2bfloat16(v);
    }
}

// ---------------- P2: weights -> Wb[1024][1152] bf16, K order (ky,kx,ci) ----
__global__ __launch_bounds__(256) void prep_w(
    const float* __restrict__ conv_w, const float* __restrict__ qkv_w,
    __hip_bfloat16* __restrict__ Wb)
{
    int g = blockIdx.x * 256 + threadIdx.x;    // 1024*1152
    int co = g / 1152;
    int k = g - co * 1152;
    int kk = k >> 7, ci = k & 127;             // kk = ky*3+kx
    float v;
    if (co < 256) v = conv_w[((size_t)(co * 128 + ci) * 9) + kk];
    else          v = qkv_w[((size_t)((co - 256) * 128 + ci) * 9) + kk];
    Wb[(size_t)co * 1152 + k] = __float2bfloat16(v);
}

// ---------------- P3: att_w fp32 -> bf16 ----------------
__global__ __launch_bounds__(256) void prep_aw(
    const float* __restrict__ att_w, __hip_bfloat16* __restrict__ Wab)
{
    int g = blockIdx.x * 256 + threadIdx.x;    // 65536
    Wab[g] = __float2bfloat16(att_w[g]);
}

// ---------------- K1: MFMA implicit-GEMM 3x3 conv ----------------
__global__ __launch_bounds__(256) void conv_gemm(
    const __hip_bfloat16* __restrict__ Wb, const __hip_bfloat16* __restrict__ xT,
    const float* __restrict__ conv_b, const float* __restrict__ qkv_b,
    float* __restrict__ out,
    __hip_bfloat16* __restrict__ qbf, __hip_bfloat16* __restrict__ kbf,
    __hip_bfloat16* __restrict__ vtb)
{
    __shared__ __align__(16) __hip_bfloat16 As[128 * 128];
    __shared__ __align__(16) __hip_bfloat16 Bs[128 * 128];

    const int tid = threadIdx.x;
    const int wv = tid >> 6;
    const int lane = tid & 63;
    const int n16 = lane & 15;
    const int quad = lane >> 4;
    const int co0 = blockIdx.x * 128;
    const int y0 = blockIdx.y * 4;
    const int b = blockIdx.z;
    const int mh = wv >> 1, nh = wv & 1;

    const int rbase = tid >> 4;
    const int hh = tid & 15;
    const int swz = (hh ^ rbase) * 8;
    const __hip_bfloat16* aGbase = Wb + (size_t)(co0 + rbase) * 1152 + hh * 8;

    f32x4 acc[4][4];
#pragma unroll
    for (int i = 0; i < 4; ++i)
#pragma unroll
        for (int j = 0; j < 4; ++j) acc[i][j] = (f32x4){0.f, 0.f, 0.f, 0.f};

    s8v ra[8], rb[8];

    auto load_tile = [&](int kk, s8v* la, s8v* lb) {
        const int ky = kk / 3, kx = kk - ky * 3;
#pragma unroll
        for (int i = 0; i < 8; ++i)
            la[i] = *reinterpret_cast<const s8v*>(aGbase + (size_t)(16 * i) * 1152 + kk * 128);
#pragma unroll
        for (int i = 0; i < 8; ++i) {
            int p = rbase + 16 * i;
            int row = y0 + (p >> 5) + ky;
            int xx = (p & 31) + kx;
            lb[i] = *reinterpret_cast<const s8v*>(
                xT + ((size_t)(b * 34 + row) * 34 + xx) * 128 + hh * 8);
        }
    };

    load_tile(0, ra, rb);

    for (int s = 0; s < 9; ++s) {
        __syncthreads();
#pragma unroll
        for (int i = 0; i < 8; ++i) {
            *reinterpret_cast<s8v*>(&As[(rbase + 16 * i) * 128 + swz]) = ra[i];
            *reinterpret_cast<s8v*>(&Bs[(rbase + 16 * i) * 128 + swz]) = rb[i];
        }
        __syncthreads();
        if (s < 8) load_tile(s + 1, ra, rb);

#pragma unroll
        for (int ksub = 0; ksub < 4; ++ksub) {
            const int chunk = ((ksub * 4 + quad) ^ n16) * 8;
            s8v af[4], bfr[4];
#pragma unroll
            for (int mt = 0; mt < 4; ++mt)
                af[mt] = *reinterpret_cast<const s8v*>(&As[(mh * 64 + mt * 16 + n16) * 128 + chunk]);
#pragma unroll
            for (int nt = 0; nt < 4; ++nt)
                bfr[nt] = *reinterpret_cast<const s8v*>(&Bs[(nh * 64 + nt * 16 + n16) * 128 + chunk]);
#pragma unroll
            for (int mt = 0; mt < 4; ++mt)
#pragma unroll
                for (int nt = 0; nt < 4; ++nt)
                    acc[mt][nt] = __builtin_amdgcn_mfma_f32_16x16x32_bf16(af[mt], bfr[nt], acc[mt][nt], 0, 0, 0);
        }
    }

    const int coBase = co0 + mh * 64;
    const int pixBase = y0 * 32 + nh * 64;
    const int seg = coBase >> 8;

    if (seg == 0) {
#pragma unroll
        for (int mt = 0; mt < 4; ++mt)
#pragma unroll
            for (int r = 0; r < 4; ++r) {
                int co = coBase + mt * 16 + quad * 4 + r;
                float bias = conv_b[co];
                float* op = out + (size_t)(b * 512 + co) * HWP + pixBase;
#pragma unroll
                for (int nt = 0; nt < 4; ++nt)
                    op[nt * 16 + n16] = acc[mt][nt][r] + bias;
            }
    } else if (seg == 1) {
        const float scale = 0.17677669529663687f;
#pragma unroll
        for (int mt = 0; mt < 4; ++mt)
#pragma unroll
            for (int r = 0; r < 4; ++r) {
                int c2 = coBase - 256 + mt * 16 + quad * 4 + r;
                float bias = qkv_b[c2];
                int h = c2 >> 5, d = c2 & 31;
                int bh = b * NHEAD + h;
#pragma unroll
                for (int nt = 0; nt < 4; ++nt) {
                    int pix = pixBase + nt * 16 + n16;
                    qbf[((size_t)bh * HWP + pix) * 32 + d] =
                        __float2bfloat16((acc[mt][nt][r] + bias) * scale);
                }
            }
    } else if (seg == 2) {
#pragma unroll
        for (int mt = 0; mt < 4; ++mt)
#pragma unroll
            for (int r = 0; r < 4; ++r) {
                int c2 = coBase - 512 + mt * 16 + quad * 4 + r;
                float bias = qkv_b[c2 + 256];
                int h = c2 >> 5, d = c2 & 31;
                int bh = b * NHEAD + h;
#pragma unroll
                for (int nt = 0; nt < 4; ++nt) {
                    int pix = pixBase + nt * 16 + n16;
                    kbf[((size_t)bh * HWP + pix) * 32 + d] =
                        __float2bfloat16(acc[mt][nt][r] + bias);
                }
            }
    } else {
#pragma unroll
        for (int mt = 0; mt < 4; ++mt)
#pragma unroll
            for (int r = 0; r < 4; ++r) {
                int c2 = coBase - 768 + mt * 16 + quad * 4 + r;
                float bias = qkv_b[c2 + 512];
                int h = c2 >> 5, d = c2 & 31;
                int bh = b * NHEAD + h;
                __hip_bfloat16* vp = vtb + ((size_t)bh * 32 + d) * HWP + pixBase;
#pragma unroll
                for (int nt = 0; nt < 4; ++nt)
                    vp[nt * 16 + n16] = __float2bfloat16(acc[mt][nt][r] + bias);
            }
    }
}

// ---------------- K2: relative logit row-vectors Rx, Ry ----------------
__global__ __launch_bounds__(256) void rel_kernel(
    const __hip_bfloat16* __restrict__ qbf,
    const float* __restrict__ kr_x, const float* __restrict__ kr_y,
    float* __restrict__ rx, float* __restrict__ ry)
{
    int g = blockIdx.x * 256 + threadIdx.x;
    int m = g & 63;
    int i = (g >> 6) & 1023;
    int bh = g >> 16;
    int yi = i >> 5, xi = i & 31;

    const __hip_bfloat16* qrow;
    const float* kr;
    float* dst;
    if (m < 32) {
        qrow = qbf + ((size_t)bh * HWP + i) * 32;
        kr = kr_x + (m - xi + 31) * 32;
        dst = rx + ((size_t)bh * HWP + i) * 32 + m;
    } else {
        int y2 = m - 32;
        qrow = qbf + ((size_t)bh * HWP + (xi * 32 + yi)) * 32;
        kr = kr_y + (y2 - xi + 31) * 32;
        dst = ry + ((size_t)bh * HWP + i) * 32 + y2;
    }
    float s = 0.f;
#pragma unroll
    for (int c = 0; c < 4; ++c) {
        s8v qa = *reinterpret_cast<const s8v*>(qrow + c * 8);
        const float* kp = kr + c * 8;
#pragma unroll
        for (int j = 0; j < 8; ++j) s += bf2f(qa[j]) * kp[j];
    }
    *dst = s;
}

// ---------------- K3: MFMA flash attention, deferred normalization ----------
// No online softmax: logits bounded (|s| << 80), so p = exp(s) unnormalized;
// per-lane lsum accumulated with zero cross-lane ops in the loop; single
// reduction + normalize at the end.
// grid (32 bh, 16 iblk): all i-blocks of a bh on one XCD (id%8 = bh%8).
__global__ __launch_bounds__(256) void attn_kernel(
    const __hip_bfloat16* __restrict__ qbf, const __hip_bfloat16* __restrict__ kbf,
    const __hip_bfloat16* __restrict__ vtb,
    const float* __restrict__ rx, const float* __restrict__ ry,
    __hip_bfloat16* __restrict__ attc)
{
    // P buffer: stride 40 bf16 (80 B): rows 16B-aligned, write conflicts 4-way,
    // read conflicts 2-way (free).
    __shared__ __align__(16) __hip_bfloat16 Pb[4][16][40];

    const int tid = threadIdx.x;
    const int wv = tid >> 6;
    const int lane = tid & 63;
    const int n16 = lane & 15;
    const int quad = lane >> 4;
    const int bh = blockIdx.x;
    const int i0 = (blockIdx.y * 4 + wv) * 16;

    const size_t qoff = ((size_t)bh * HWP + i0 + n16) * 32 + quad * 8;
    s8v aq = *reinterpret_cast<const s8v*>(qbf + qoff);

    float rx0[4], rx1[4];
#pragma unroll
    for (int r = 0; r < 4; ++r) {
        const float* rp = rx + ((size_t)bh * HWP + i0 + quad * 4 + r) * 32;
        rx0[r] = rp[n16];
        rx1[r] = rp[n16 + 16];
    }
    const float* ryrow[4];
#pragma unroll
    for (int r = 0; r < 4; ++r)
        ryrow[r] = ry + ((size_t)bh * HWP + i0 + quad * 4 + r) * 32;

    float lsum[4] = {0.f, 0.f, 0.f, 0.f};
    f32x4 O0 = {0.f, 0.f, 0.f, 0.f}, O1 = {0.f, 0.f, 0.f, 0.f};

    const __hip_bfloat16* kbase = kbf + (size_t)bh * HWP * 32;
    const __hip_bfloat16* vbase = vtb + (size_t)bh * 32 * HWP;

    // prefetch jt=0 fragments
    s8v bk0 = *reinterpret_cast<const s8v*>(kbase + ((size_t)n16 * 32 + quad * 8));
    s8v bk1 = *reinterpret_cast<const s8v*>(kbase + ((size_t)(16 + n16) * 32 + quad * 8));
    s8v bv0 = *reinterpret_cast<const s8v*>(vbase + ((size_t)n16 * HWP + quad * 8));
    s8v bv1 = *reinterpret_cast<const s8v*>(vbase + ((size_t)(n16 + 16) * HWP + quad * 8));

    for (int jt4 = 0; jt4 < 8; ++jt4) {
        float4 ryc[4];
#pragma unroll
        for (int r = 0; r < 4; ++r)
            ryc[r] = *(const float4*)(ryrow[r] + jt4 * 4);

#pragma unroll
        for (int u = 0; u < 4; ++u) {
            const int jt = jt4 * 4 + u;
            s8v cbk0 = bk0, cbk1 = bk1, cbv0 = bv0, cbv1 = bv1;
            if (jt < 31) {
                const int jn = (jt + 1) * 32;
                bk0 = *reinterpret_cast<const s8v*>(kbase + ((size_t)(jn + n16) * 32 + quad * 8));
                bk1 = *reinterpret_cast<const s8v*>(kbase + ((size_t)(jn + 16 + n16) * 32 + quad * 8));
                bv0 = *reinterpret_cast<const s8v*>(vbase + ((size_t)n16 * HWP + jn + quad * 8));
                bv1 = *reinterpret_cast<const s8v*>(vbase + ((size_t)(n16 + 16) * HWP + jn + quad * 8));
            }

            f32x4 s0 = {0.f, 0.f, 0.f, 0.f}, s1 = {0.f, 0.f, 0.f, 0.f};
            s0 = __builtin_amdgcn_mfma_f32_16x16x32_bf16(aq, cbk0, s0, 0, 0, 0);
            s1 = __builtin_amdgcn_mfma_f32_16x16x32_bf16(aq, cbk1, s1, 0, 0, 0);

#pragma unroll
            for (int r = 0; r < 4; ++r) {
                float ryv = (u == 0) ? ryc[r].x : (u == 1) ? ryc[r].y : (u == 2) ? ryc[r].z : ryc[r].w;
                float p0 = __expf(s0[r] + rx0[r] + ryv);
                float p1 = __expf(s1[r] + rx1[r] + ryv);
                lsum[r] += p0 + p1;
                Pb[wv][quad * 4 + r][n16]      = __float2bfloat16(p0);
                Pb[wv][quad * 4 + r][n16 + 16] = __float2bfloat16(p1);
            }
            s8v pA = *reinterpret_cast<const s8v*>(&Pb[wv][n16][quad * 8]);
            O0 = __builtin_amdgcn_mfma_f32_16x16x32_bf16(pA, cbv0, O0, 0, 0, 0);
            O1 = __builtin_amdgcn_mfma_f32_16x16x32_bf16(pA, cbv1, O1, 0, 0, 0);
        }
    }

    const int b = bh >> 3, h = bh & 7;
#pragma unroll
    for (int r = 0; r < 4; ++r) {
        float l = lsum[r];
        l += __shfl_xor(l, 1);
        l += __shfl_xor(l, 2);
        l += __shfl_xor(l, 4);
        l += __shfl_xor(l, 8);
        float inv = 1.0f / l;
        int i = i0 + quad * 4 + r;
        int yi = i >> 5, xi = i & 31;
        __hip_bfloat16* op = attc + ((size_t)(b * 256 + h * 32 + yi) * 32 + xi) * 32;
        op[n16] = __float2bfloat16(O0[r] * inv);
        op[n16 + 16] = __float2bfloat16(O1[r] * inv);
    }
}

// ---------------- K4a: transpose attc[b][c][pix] -> attT[b][pix][c] ----------
__global__ __launch_bounds__(256) void trans_att(
    const __hip_bfloat16* __restrict__ attc, __hip_bfloat16* __restrict__ attT)
{
    __shared__ __align__(16) __hip_bfloat16 Ls[64][264];
    const int tid = threadIdx.x;
    const int p0 = blockIdx.x * 64;
    const int b = blockIdx.y;

#pragma unroll
    for (int pass = 0; pass < 8; ++pass) {
        int ch = pass * 32 + (tid >> 3);
        int pg = (tid & 7) * 8;
        s8v v = *reinterpret_cast<const s8v*>(
            attc + ((size_t)(b * 256 + ch) * HWP) + p0 + pg);
#pragma unroll
        for (int j = 0; j < 8; ++j)
            Ls[pg + j][ch] = ((const __hip_bfloat16*)&v)[j];
    }
    __syncthreads();

    const int pix = tid >> 2;
    const int cb = (tid & 3) * 64;
    __hip_bfloat16* op = attT + ((size_t)(b * HWP + p0 + pix)) * 256 + cb;
#pragma unroll
    for (int g = 0; g < 8; ++g) {
        s8v v = *reinterpret_cast<const s8v*>(&Ls[pix][cb + g * 8]);
        *reinterpret_cast<s8v*>(op + g * 8) = v;
    }
}

// ---------------- K4b: 1x1 conv as MFMA GEMM, no LDS ----------------
__global__ __launch_bounds__(256) void conv1x1_gemm(
    const __hip_bfloat16* __restrict__ Wab, const __hip_bfloat16* __restrict__ attT,
    const float* __restrict__ att_b, float* __restrict__ out)
{
    const int tid = threadIdx.x;
    const int wv = tid >> 6;
    const int lane = tid & 63;
    const int n16 = lane & 15;
    const int quad = lane >> 4;
    const int o0 = blockIdx.x * 64;
    const int p0 = blockIdx.y * 64;
    const int b = blockIdx.z;
    const int oW = o0 + (wv >> 1) * 32;
    const int pW = p0 + (wv & 1) * 32;

    f32x4 acc[2][2];
#pragma unroll
    for (int i = 0; i < 2; ++i)
#pragma unroll
        for (int j = 0; j < 2; ++j) acc[i][j] = (f32x4){0.f, 0.f, 0.f, 0.f};

#pragma unroll
    for (int ks = 0; ks < 8; ++ks) {
        const int c0 = ks * 32 + quad * 8;
        s8v a0 = *reinterpret_cast<const s8v*>(Wab + (size_t)(oW + n16) * 256 + c0);
        s8v a1 = *reinterpret_cast<const s8v*>(Wab + (size_t)(oW + 16 + n16) * 256 + c0);
        s8v b0 = *reinterpret_cast<const s8v*>(attT + ((size_t)(b * HWP + pW + n16)) * 256 + c0);
        s8v b1 = *reinterpret_cast<const s8v*>(attT + ((size_t)(b * HWP + pW + 16 + n16)) * 256 + c0);
        acc[0][0] = __builtin_amdgcn_mfma_f32_16x16x32_bf16(a0, b0, acc[0][0], 0, 0, 0);
        acc[0][1] = __builtin_amdgcn_mfma_f32_16x16x32_bf16(a0, b1, acc[0][1], 0, 0, 0);
        acc[1][0] = __builtin_amdgcn_mfma_f32_16x16x32_bf16(a1, b0, acc[1][0], 0, 0, 0);
        acc[1][1] = __builtin_amdgcn_mfma_f32_16x16x32_bf16(a1, b1, acc[1][1], 0, 0, 0);
    }

#pragma unroll
    for (int mt = 0; mt < 2; ++mt)
#pragma unroll
        for (int r = 0; r < 4; ++r) {
            int o = oW + mt * 16 + quad * 4 + r;
            float bias = att_b[o];
            float* op = out + ((size_t)(b * 512 + 256 + o)) * HWP;
#pragma unroll
            for (int nt = 0; nt < 2; ++nt)
                op[pW + nt * 16 + n16] = acc[mt][nt][r] + bias;
        }
}

extern "C" void kernel_launch(void* const* d_in, const int* in_sizes, int n_in,
                              void* d_out, int out_size, void* d_ws, size_t ws_size,
                              hipStream_t stream) {
    const float* x      = (const float*)d_in[0];
    const float* conv_w = (const float*)d_in[1];
    const float* conv_b = (const float*)d_in[2];
    const float* qkv_w  = (const float*)d_in[3];
    const float* qkv_b  = (const float*)d_in[4];
    const float* att_w  = (const float*)d_in[5];
    const float* att_b  = (const float*)d_in[6];
    const float* kr_x   = (const float*)d_in[7];
    const float* kr_y   = (const float*)d_in[8];
    float* out = (float*)d_out;

    char* base = (char*)d_ws;
    const size_t MB = 1u << 20;
    float* rxb = (float*)(base + 0);
    float* ryb = (float*)(base + 4 * MB);
    __hip_bfloat16* qbf  = (__hip_bfloat16*)(base + 8 * MB);
    __hip_bfloat16* kbf  = (__hip_bfloat16*)(base + 10 * MB);
    __hip_bfloat16* vtb  = (__hip_bfloat16*)(base + 12 * MB);
    __hip_bfloat16* xT   = (__hip_bfloat16*)(base + 14 * MB);
    __hip_bfloat16* Wb   = (__hip_bfloat16*)(base + 16 * MB);
    __hip_bfloat16* attc = (__hip_bfloat16*)(base + 19 * MB);
    __hip_bfloat16* attT = (__hip_bfloat16*)(base + 21 * MB);
    __hip_bfloat16* Wab  = (__hip_bfloat16*)(base + 23 * MB);

    prep_xT<<<dim3(34, 4), 256, 0, stream>>>(x, xT);
    prep_w<<<dim3(4608), 256, 0, stream>>>(conv_w, qkv_w, Wb);
    prep_aw<<<dim3(256), 256, 0, stream>>>(att_w, Wab);
    conv_gemm<<<dim3(8, 8, 4), 256, 0, stream>>>(
        Wb, xT, conv_b, qkv_b, out, qbf, kbf, vtb);
    rel_kernel<<<dim3(8192), 256, 0, stream>>>(qbf, kr_x, kr_y, rxb, ryb);
    attn_kernel<<<dim3(32, 16), 256, 0, stream>>>(qbf, kbf, vtb, rxb, ryb, attc);
    trans_att<<<dim3(16, 4), 256, 0, stream>>>(attc, attT);
    conv1x1_gemm<<<dim3(4, 16, 4), 256, 0, stream>>>(Wab, attT, att_b, out);
}

// Round 7
// 140.764 us; speedup vs baseline: 1.3847x; 1.3847x over previous
//
#include <hip/hip_runtime.h>
#include <hip/hip_bf16.h>
#include <math.h>

#define BN 4
#define CIN 128
#define HH 32
#define WW 32
#define HWP 1024
#define NHEAD 8

typedef __attribute__((ext_vector_type(8))) short s8v;
typedef __attribute__((ext_vector_type(4))) float f32x4;

// ---------------- P: all prep in one kernel ----------------
// blocks [0,4608): Wb;  [4608,4744): xT;  [4744,5000): Wab;  5000: krb
__global__ __launch_bounds__(256) void prep_all(
    const float* __restrict__ x,
    const float* __restrict__ conv_w, const float* __restrict__ qkv_w,
    const float* __restrict__ att_w,
    const float* __restrict__ kr_x, const float* __restrict__ kr_y,
    __hip_bfloat16* __restrict__ xT, __hip_bfloat16* __restrict__ Wb,
    __hip_bfloat16* __restrict__ Wab, __hip_bfloat16* __restrict__ krb)
{
    const int bid = blockIdx.x;
    const int tid = threadIdx.x;

    if (bid < 4608) {
        int g = bid * 256 + tid;               // 1024*1152
        int co = g / 1152;
        int k = g - co * 1152;
        int kk = k >> 7, ci = k & 127;         // kk = ky*3+kx
        float v;
        if (co < 256) v = conv_w[((size_t)(co * 128 + ci) * 9) + kk];
        else          v = qkv_w[((size_t)((co - 256) * 128 + ci) * 9) + kk];
        Wb[(size_t)co * 1152 + k] = __float2bfloat16(v);
    } else if (bid < 4744) {
        __shared__ float xs[CIN][33];
        int rel = bid - 4608;
        int yy = rel >> 2;
        int b = rel & 3;
        const bool inner = (yy >= 1 && yy <= 32);
        if (inner) {
            for (int idx = tid; idx < CIN * 32; idx += 256) {
                int ci = idx >> 5, xx = idx & 31;
                xs[ci][xx] = x[((size_t)(b * CIN + ci) * HH + (yy - 1)) * WW + xx];
            }
        }
        __syncthreads();
        for (int idx = tid; idx < 34 * 128; idx += 256) {
            int xx = idx >> 7, ci = idx & 127;
            float v = 0.f;
            if (inner && xx >= 1 && xx <= 32) v = xs[ci][xx - 1];
            xT[((size_t)(b * 34 + yy) * 34 + xx) * 128 + ci] = __float2bfloat16(v);
        }
    } else if (bid < 5000) {
        int g = (bid - 4744) * 256 + tid;      // 65536
        Wab[g] = __float2bfloat16(att_w[g]);
    } else {
        // krb[axis][64][32]; col 63 zeroed (d_ws is poisoned!)
        for (int idx = tid; idx < 2 * 64 * 32; idx += 256) {
            int axis = idx >> 11;
            int col = (idx >> 5) & 63;
            int d = idx & 31;
            float v = 0.f;
            if (col < 63) v = axis ? kr_y[col * 32 + d] : kr_x[col * 32 + d];
            krb[idx] = __float2bfloat16(v);
        }
    }
}

// ---------------- K1: MFMA implicit-GEMM 3x3 conv ----------------
__global__ __launch_bounds__(256) void conv_gemm(
    const __hip_bfloat16* __restrict__ Wb, const __hip_bfloat16* __restrict__ xT,
    const float* __restrict__ conv_b, const float* __restrict__ qkv_b,
    float* __restrict__ out,
    __hip_bfloat16* __restrict__ qbf, __hip_bfloat16* __restrict__ kbf,
    __hip_bfloat16* __restrict__ vtb)
{
    __shared__ __align__(16) __hip_bfloat16 As[128 * 128];
    __shared__ __align__(16) __hip_bfloat16 Bs[128 * 128];

    const int tid = threadIdx.x;
    const int wv = tid >> 6;
    const int lane = tid & 63;
    const int n16 = lane & 15;
    const int quad = lane >> 4;
    const int co0 = blockIdx.x * 128;
    const int y0 = blockIdx.y * 4;
    const int b = blockIdx.z;
    const int mh = wv >> 1, nh = wv & 1;

    const int rbase = tid >> 4;
    const int hh = tid & 15;
    const int swz = (hh ^ rbase) * 8;
    const __hip_bfloat16* aGbase = Wb + (size_t)(co0 + rbase) * 1152 + hh * 8;

    f32x4 acc[4][4];
#pragma unroll
    for (int i = 0; i < 4; ++i)
#pragma unroll
        for (int j = 0; j < 4; ++j) acc[i][j] = (f32x4){0.f, 0.f, 0.f, 0.f};

    s8v ra[8], rb[8];

    auto load_tile = [&](int kk, s8v* la, s8v* lb) {
        const int ky = kk / 3, kx = kk - ky * 3;
#pragma unroll
        for (int i = 0; i < 8; ++i)
            la[i] = *reinterpret_cast<const s8v*>(aGbase + (size_t)(16 * i) * 1152 + kk * 128);
#pragma unroll
        for (int i = 0; i < 8; ++i) {
            int p = rbase + 16 * i;
            int row = y0 + (p >> 5) + ky;
            int xx = (p & 31) + kx;
            lb[i] = *reinterpret_cast<const s8v*>(
                xT + ((size_t)(b * 34 + row) * 34 + xx) * 128 + hh * 8);
        }
    };

    load_tile(0, ra, rb);

    for (int s = 0; s < 9; ++s) {
        __syncthreads();
#pragma unroll
        for (int i = 0; i < 8; ++i) {
            *reinterpret_cast<s8v*>(&As[(rbase + 16 * i) * 128 + swz]) = ra[i];
            *reinterpret_cast<s8v*>(&Bs[(rbase + 16 * i) * 128 + swz]) = rb[i];
        }
        __syncthreads();
        if (s < 8) load_tile(s + 1, ra, rb);

#pragma unroll
        for (int ksub = 0; ksub < 4; ++ksub) {
            const int chunk = ((ksub * 4 + quad) ^ n16) * 8;
            s8v af[4], bfr[4];
#pragma unroll
            for (int mt = 0; mt < 4; ++mt)
                af[mt] = *reinterpret_cast<const s8v*>(&As[(mh * 64 + mt * 16 + n16) * 128 + chunk]);
#pragma unroll
            for (int nt = 0; nt < 4; ++nt)
                bfr[nt] = *reinterpret_cast<const s8v*>(&Bs[(nh * 64 + nt * 16 + n16) * 128 + chunk]);
#pragma unroll
            for (int mt = 0; mt < 4; ++mt)
#pragma unroll
                for (int nt = 0; nt < 4; ++nt)
                    acc[mt][nt] = __builtin_amdgcn_mfma_f32_16x16x32_bf16(af[mt], bfr[nt], acc[mt][nt], 0, 0, 0);
        }
    }

    const int coBase = co0 + mh * 64;
    const int pixBase = y0 * 32 + nh * 64;
    const int seg = coBase >> 8;

    if (seg == 0) {
#pragma unroll
        for (int mt = 0; mt < 4; ++mt)
#pragma unroll
            for (int r = 0; r < 4; ++r) {
                int co = coBase + mt * 16 + quad * 4 + r;
                float bias = conv_b[co];
                float* op = out + (size_t)(b * 512 + co) * HWP + pixBase;
#pragma unroll
                for (int nt = 0; nt < 4; ++nt)
                    op[nt * 16 + n16] = acc[mt][nt][r] + bias;
            }
    } else if (seg == 1) {
        const float scale = 0.17677669529663687f;
#pragma unroll
        for (int mt = 0; mt < 4; ++mt)
#pragma unroll
            for (int r = 0; r < 4; ++r) {
                int c2 = coBase - 256 + mt * 16 + quad * 4 + r;
                float bias = qkv_b[c2];
                int h = c2 >> 5, d = c2 & 31;
                int bh = b * NHEAD + h;
#pragma unroll
                for (int nt = 0; nt < 4; ++nt) {
                    int pix = pixBase + nt * 16 + n16;
                    qbf[((size_t)bh * HWP + pix) * 32 + d] =
                        __float2bfloat16((acc[mt][nt][r] + bias) * scale);
                }
            }
    } else if (seg == 2) {
#pragma unroll
        for (int mt = 0; mt < 4; ++mt)
#pragma unroll
            for (int r = 0; r < 4; ++r) {
                int c2 = coBase - 512 + mt * 16 + quad * 4 + r;
                float bias = qkv_b[c2 + 256];
                int h = c2 >> 5, d = c2 & 31;
                int bh = b * NHEAD + h;
#pragma unroll
                for (int nt = 0; nt < 4; ++nt) {
                    int pix = pixBase + nt * 16 + n16;
                    kbf[((size_t)bh * HWP + pix) * 32 + d] =
                        __float2bfloat16(acc[mt][nt][r] + bias);
                }
            }
    } else {
#pragma unroll
        for (int mt = 0; mt < 4; ++mt)
#pragma unroll
            for (int r = 0; r < 4; ++r) {
                int c2 = coBase - 768 + mt * 16 + quad * 4 + r;
                float bias = qkv_b[c2 + 512];
                int h = c2 >> 5, d = c2 & 31;
                int bh = b * NHEAD + h;
                __hip_bfloat16* vp = vtb + ((size_t)bh * 32 + d) * HWP + pixBase;
#pragma unroll
                for (int nt = 0; nt < 4; ++nt)
                    vp[nt * 16 + n16] = __float2bfloat16(acc[mt][nt][r] + bias);
            }
    }
}

// ---------------- K2: MFMA flash attention with fused rel logits ----------
// QR[i][m] = q_i . kr[m] computed by MFMA into wave-private LDS; skew windows
// Rx[i][xj] = QRx[i][xj+31-xi], Ry[i][yj] = QRy[i][yj+31-xi] read from LDS.
// Deferred normalization (no online softmax; logits bounded).
__global__ __launch_bounds__(256) void attn_kernel(
    const __hip_bfloat16* __restrict__ qbf, const __hip_bfloat16* __restrict__ kbf,
    const __hip_bfloat16* __restrict__ vtb, const __hip_bfloat16* __restrict__ krb,
    __hip_bfloat16* __restrict__ attc)
{
    __shared__ __align__(16) float QrX[4][16][68];
    __shared__ __align__(16) float QrY[4][16][68];
    __shared__ __align__(16) __hip_bfloat16 Pb[4][16][40];

    const int tid = threadIdx.x;
    const int wv = tid >> 6;
    const int lane = tid & 63;
    const int n16 = lane & 15;
    const int quad = lane >> 4;
    const int bh = blockIdx.x;
    const int i0 = (blockIdx.y * 4 + wv) * 16;
    const int xi0 = i0 & 31;
    const int yi0 = i0 >> 5;

    // Q fragment (A layout): row i0+n16, k = quad*8..+8
    s8v aq = *reinterpret_cast<const s8v*>(
        qbf + ((size_t)bh * HWP + i0 + n16) * 32 + quad * 8);
    // Q at transposed pixel (for Ry): row t -> pixel (xi0+t)*32 + yi0
    s8v aqT = *reinterpret_cast<const s8v*>(
        qbf + ((size_t)bh * HWP + (xi0 + n16) * 32 + yi0) * 32 + quad * 8);

    // rel-logit MFMAs: QR tiles 16x64 into wave-private LDS
#pragma unroll
    for (int t = 0; t < 4; ++t) {
        s8v bx = *reinterpret_cast<const s8v*>(krb + ((size_t)(t * 16 + n16)) * 32 + quad * 8);
        s8v by = *reinterpret_cast<const s8v*>(krb + ((size_t)(64 + t * 16 + n16)) * 32 + quad * 8);
        f32x4 cx = {0.f, 0.f, 0.f, 0.f}, cy = {0.f, 0.f, 0.f, 0.f};
        cx = __builtin_amdgcn_mfma_f32_16x16x32_bf16(aq, bx, cx, 0, 0, 0);
        cy = __builtin_amdgcn_mfma_f32_16x16x32_bf16(aqT, by, cy, 0, 0, 0);
#pragma unroll
        for (int r = 0; r < 4; ++r) {
            QrX[wv][quad * 4 + r][t * 16 + n16] = cx[r];
            QrY[wv][quad * 4 + r][t * 16 + n16] = cy[r];
        }
    }

    // window reads (wave-private; compiler inserts lgkmcnt)
    float rx0[4], rx1[4];
    int rybase[4];
#pragma unroll
    for (int r = 0; r < 4; ++r) {
        int xi = xi0 + quad * 4 + r;
        rx0[r] = QrX[wv][quad * 4 + r][n16 + 31 - xi];
        rx1[r] = QrX[wv][quad * 4 + r][n16 + 47 - xi];
        rybase[r] = 31 - xi;
    }

    float lsum[4] = {0.f, 0.f, 0.f, 0.f};
    f32x4 O0 = {0.f, 0.f, 0.f, 0.f}, O1 = {0.f, 0.f, 0.f, 0.f};

    const __hip_bfloat16* kbase = kbf + (size_t)bh * HWP * 32;
    const __hip_bfloat16* vbase = vtb + (size_t)bh * 32 * HWP;

    s8v bk0 = *reinterpret_cast<const s8v*>(kbase + ((size_t)n16 * 32 + quad * 8));
    s8v bk1 = *reinterpret_cast<const s8v*>(kbase + ((size_t)(16 + n16) * 32 + quad * 8));
    s8v bv0 = *reinterpret_cast<const s8v*>(vbase + ((size_t)n16 * HWP + quad * 8));
    s8v bv1 = *reinterpret_cast<const s8v*>(vbase + ((size_t)(n16 + 16) * HWP + quad * 8));

    for (int jt = 0; jt < 32; ++jt) {
        s8v cbk0 = bk0, cbk1 = bk1, cbv0 = bv0, cbv1 = bv1;
        if (jt < 31) {
            const int jn = (jt + 1) * 32;
            bk0 = *reinterpret_cast<const s8v*>(kbase + ((size_t)(jn + n16) * 32 + quad * 8));
            bk1 = *reinterpret_cast<const s8v*>(kbase + ((size_t)(jn + 16 + n16) * 32 + quad * 8));
            bv0 = *reinterpret_cast<const s8v*>(vbase + ((size_t)n16 * HWP + jn + quad * 8));
            bv1 = *reinterpret_cast<const s8v*>(vbase + ((size_t)(n16 + 16) * HWP + jn + quad * 8));
        }

        f32x4 s0 = {0.f, 0.f, 0.f, 0.f}, s1 = {0.f, 0.f, 0.f, 0.f};
        s0 = __builtin_amdgcn_mfma_f32_16x16x32_bf16(aq, cbk0, s0, 0, 0, 0);
        s1 = __builtin_amdgcn_mfma_f32_16x16x32_bf16(aq, cbk1, s1, 0, 0, 0);

#pragma unroll
        for (int r = 0; r < 4; ++r) {
            float ryv = QrY[wv][quad * 4 + r][jt + rybase[r]];
            float p0 = __expf(s0[r] + rx0[r] + ryv);
            float p1 = __expf(s1[r] + rx1[r] + ryv);
            lsum[r] += p0 + p1;
            Pb[wv][quad * 4 + r][n16]      = __float2bfloat16(p0);
            Pb[wv][quad * 4 + r][n16 + 16] = __float2bfloat16(p1);
        }
        s8v pA = *reinterpret_cast<const s8v*>(&Pb[wv][n16][quad * 8]);
        O0 = __builtin_amdgcn_mfma_f32_16x16x32_bf16(pA, cbv0, O0, 0, 0, 0);
        O1 = __builtin_amdgcn_mfma_f32_16x16x32_bf16(pA, cbv1, O1, 0, 0, 0);
    }

    const int b = bh >> 3, h = bh & 7;
#pragma unroll
    for (int r = 0; r < 4; ++r) {
        float l = lsum[r];
        l += __shfl_xor(l, 1);
        l += __shfl_xor(l, 2);
        l += __shfl_xor(l, 4);
        l += __shfl_xor(l, 8);
        float inv = 1.0f / l;
        int i = i0 + quad * 4 + r;
        int yi = i >> 5, xi = i & 31;
        __hip_bfloat16* op = attc + ((size_t)(b * 256 + h * 32 + yi) * 32 + xi) * 32;
        op[n16] = __float2bfloat16(O0[r] * inv);
        op[n16 + 16] = __float2bfloat16(O1[r] * inv);
    }
}

// ---------------- K3: 1x1 conv MFMA GEMM with fused transpose staging -------
// grid (4 o-tiles, 16 pix-tiles, 4 b); LDS holds [64 pix][256 c] of attc.
__global__ __launch_bounds__(256) void conv1x1_gemm(
    const __hip_bfloat16* __restrict__ Wab, const __hip_bfloat16* __restrict__ attc,
    const float* __restrict__ att_b, float* __restrict__ out)
{
    __shared__ __align__(16) __hip_bfloat16 Ls[64][264];

    const int tid = threadIdx.x;
    const int wv = tid >> 6;
    const int lane = tid & 63;
    const int n16 = lane & 15;
    const int quad = lane >> 4;
    const int o0 = blockIdx.x * 64;
    const int p0 = blockIdx.y * 64;
    const int b = blockIdx.z;
    const int oW = o0 + (wv >> 1) * 32;
    const int pL = (wv & 1) * 32;      // local pix base in LDS

    // stage attc[256 c][64 pix] -> Ls[pix][c]
#pragma unroll
    for (int pass = 0; pass < 8; ++pass) {
        int ch = pass * 32 + (tid >> 3);
        int pg = (tid & 7) * 8;
        s8v v = *reinterpret_cast<const s8v*>(
            attc + ((size_t)(b * 256 + ch) * HWP) + p0 + pg);
#pragma unroll
        for (int j = 0; j < 8; ++j)
            Ls[pg + j][ch] = ((const __hip_bfloat16*)&v)[j];
    }
    __syncthreads();

    f32x4 acc[2][2];
#pragma unroll
    for (int i = 0; i < 2; ++i)
#pragma unroll
        for (int j = 0; j < 2; ++j) acc[i][j] = (f32x4){0.f, 0.f, 0.f, 0.f};

#pragma unroll
    for (int ks = 0; ks < 8; ++ks) {
        const int c0 = ks * 32 + quad * 8;
        s8v a0 = *reinterpret_cast<const s8v*>(Wab + (size_t)(oW + n16) * 256 + c0);
        s8v a1 = *reinterpret_cast<const s8v*>(Wab + (size_t)(oW + 16 + n16) * 256 + c0);
        s8v b0 = *reinterpret_cast<const s8v*>(&Ls[pL + n16][c0]);
        s8v b1 = *reinterpret_cast<const s8v*>(&Ls[pL + 16 + n16][c0]);
        acc[0][0] = __builtin_amdgcn_mfma_f32_16x16x32_bf16(a0, b0, acc[0][0], 0, 0, 0);
        acc[0][1] = __builtin_amdgcn_mfma_f32_16x16x32_bf16(a0, b1, acc[0][1], 0, 0, 0);
        acc[1][0] = __builtin_amdgcn_mfma_f32_16x16x32_bf16(a1, b0, acc[1][0], 0, 0, 0);
        acc[1][1] = __builtin_amdgcn_mfma_f32_16x16x32_bf16(a1, b1, acc[1][1], 0, 0, 0);
    }

#pragma unroll
    for (int mt = 0; mt < 2; ++mt)
#pragma unroll
        for (int r = 0; r < 4; ++r) {
            int o = oW + mt * 16 + quad * 4 + r;
            float bias = att_b[o];
            float* op = out + ((size_t)(b * 512 + 256 + o)) * HWP;
#pragma unroll
            for (int nt = 0; nt < 2; ++nt)
                op[p0 + pL + nt * 16 + n16] = acc[mt][nt][r] + bias;
        }
}

extern "C" void kernel_launch(void* const* d_in, const int* in_sizes, int n_in,
                              void* d_out, int out_size, void* d_ws, size_t ws_size,
                              hipStream_t stream) {
    const float* x      = (const float*)d_in[0];
    const float* conv_w = (const float*)d_in[1];
    const float* conv_b = (const float*)d_in[2];
    const float* qkv_w  = (const float*)d_in[3];
    const float* qkv_b  = (const float*)d_in[4];
    const float* att_w  = (const float*)d_in[5];
    const float* att_b  = (const float*)d_in[6];
    const float* kr_x   = (const float*)d_in[7];
    const float* kr_y   = (const float*)d_in[8];
    float* out = (float*)d_out;

    char* base = (char*)d_ws;
    const size_t MB = 1u << 20;
    __hip_bfloat16* qbf  = (__hip_bfloat16*)(base + 0 * MB);    // 2 MB
    __hip_bfloat16* kbf  = (__hip_bfloat16*)(base + 2 * MB);    // 2 MB
    __hip_bfloat16* vtb  = (__hip_bfloat16*)(base + 4 * MB);    // 2 MB
    __hip_bfloat16* xT   = (__hip_bfloat16*)(base + 6 * MB);    // 1.13 MB
    __hip_bfloat16* Wb   = (__hip_bfloat16*)(base + 8 * MB);    // 2.25 MB
    __hip_bfloat16* attc = (__hip_bfloat16*)(base + 11 * MB);   // 2 MB
    __hip_bfloat16* Wab  = (__hip_bfloat16*)(base + 13 * MB);   // 128 KB
    __hip_bfloat16* krb  = (__hip_bfloat16*)(base + 14 * MB);   // 8 KB

    prep_all<<<dim3(5001), 256, 0, stream>>>(
        x, conv_w, qkv_w, att_w, kr_x, kr_y, xT, Wb, Wab, krb);
    conv_gemm<<<dim3(8, 8, 4), 256, 0, stream>>>(
        Wb, xT, conv_b, qkv_b, out, qbf, kbf, vtb);
    attn_kernel<<<dim3(32, 16), 256, 0, stream>>>(qbf, kbf, vtb, krb, attc);
    conv1x1_gemm<<<dim3(4, 16, 4), 256, 0, stream>>>(Wab, attc, att_b, out);
}